// Round 3
// baseline (324.569 us; speedup 1.0000x reference)
//
#include <hip/hip_runtime.h>

// Maxwell model: gamma_{n+1} = (1 - 2 dt_n) gamma_n + 2 dt_n eps_n  (affine recurrence)
// sigma_t = 3*eps_t - 2*gamma_t, sigma_0 = 0.
//
// Wave-per-row: each 64-lane wave owns one row of T=2048; each lane owns 32
// contiguous timesteps. 16 independent float4 loads in flight per wave (16KB),
// no __syncthreads, no LDS: wave-local shfl scan of the affine (P,Q) pairs,
// then sequential replay + coalesced-enough float4 stores.

#define T_LEN 2048
#define EPT 32              // elements per thread: 64 * 32 = 2048
#define ROWS_PER_BLOCK 4    // one row per wave, 256-thread blocks

__global__ __launch_bounds__(256) void maxwell_wave_kernel(
    const float* __restrict__ eps_g, const float* __restrict__ dt_g,
    float* __restrict__ out_g, int nrows)
{
    const int lane = threadIdx.x & 63;
    const int w    = threadIdx.x >> 6;
    const long row = (long)blockIdx.x * ROWS_PER_BLOCK + w;
    if (row >= nrows) return;
    const long base = row * T_LEN + (long)lane * EPT;

    // Issue all 16 loads up front (independent → deep vmcnt pipeline).
    float e[EPT], d[EPT];
    #pragma unroll
    for (int i = 0; i < EPT / 4; ++i) {
        const float4 v = *(const float4*)(eps_g + base + i * 4);
        e[4*i+0] = v.x; e[4*i+1] = v.y; e[4*i+2] = v.z; e[4*i+3] = v.w;
    }
    #pragma unroll
    for (int i = 0; i < EPT / 4; ++i) {
        const float4 v = *(const float4*)(dt_g + base + i * 4);
        d[4*i+0] = v.x; d[4*i+1] = v.y; d[4*i+2] = v.z; d[4*i+3] = v.w;
    }

    // Compose this lane's 32 transitions: g -> P*g + Q
    float P = 1.0f, Q = 0.0f;
    #pragma unroll
    for (int k = 0; k < EPT; ++k) {
        const float ad = 2.0f * d[k];
        const float A  = 1.0f - ad;
        Q = fmaf(A, Q, ad * e[k]);
        P *= A;
    }

    // Inclusive scan across the wave (affine composition is associative).
    #pragma unroll
    for (int dd = 1; dd < 64; dd <<= 1) {
        const float Pp = __shfl_up(P, dd);
        const float Qp = __shfl_up(Q, dd);
        if (lane >= dd) { Q = fmaf(P, Qp, Q); P *= Pp; }
    }

    // Exclusive prefix: gamma at t = lane*EPT. gamma_0 = 0 → only Q survives.
    float g = __shfl_up(Q, 1);
    if (lane == 0) g = 0.0f;

    // Replay the 32 local steps with the true incoming gamma; store 4 at a time.
    #pragma unroll
    for (int i = 0; i < EPT / 4; ++i) {
        float o[4];
        #pragma unroll
        for (int j = 0; j < 4; ++j) {
            const int k = 4 * i + j;
            o[j] = fmaf(3.0f, e[k], -2.0f * g);      // sigma at this t (incoming gamma)
            g = fmaf(2.0f * d[k], e[k] - g, g);      // advance gamma with step k
        }
        if (lane == 0 && i == 0) o[0] = 0.0f;        // sigma_0 = 0
        *(float4*)(out_g + base + i * 4) = make_float4(o[0], o[1], o[2], o[3]);
    }
}

extern "C" void kernel_launch(void* const* d_in, const int* in_sizes, int n_in,
                              void* d_out, int out_size, void* d_ws, size_t ws_size,
                              hipStream_t stream) {
    const float* strains = (const float*)d_in[0];
    const float* dts     = (const float*)d_in[1];
    float* out           = (float*)d_out;

    const int nrows  = in_sizes[0] / T_LEN;                     // 16384
    const int blocks = (nrows + ROWS_PER_BLOCK - 1) / ROWS_PER_BLOCK;
    maxwell_wave_kernel<<<blocks, 256, 0, stream>>>(strains, dts, out, nrows);
}